// Round 7
// baseline (431.797 us; speedup 1.0000x reference)
//
#include <hip/hip_runtime.h>
#include <hip/hip_bf16.h>
#include <stdint.h>

typedef __attribute__((ext_vector_type(8))) short bh8;
typedef __attribute__((ext_vector_type(4))) float f32x4;
typedef unsigned short u16;
typedef unsigned int u32;

#define B_    8
#define C_    512
#define LF    16384
#define KTOT  1536

// output chunk offsets (float32 elements)
#define OBJ_OFF  0
#define REG_OFF  917504      // 8 * 16384*7
#define ANC_OFF  2752512     // REG_OFF + 8*16384*14

__device__ __forceinline__ u16 f2bf(float f) {
    u32 u = __float_as_uint(f);
    return (u16)((u + 0x7FFFu + ((u >> 16) & 1u)) >> 16);
}
__device__ __forceinline__ u32 pk2bf(float lo, float hi) {
    u32 r;
    asm("v_cvt_pk_bf16_f32 %0, %1, %2" : "=v"(r) : "v"(lo), "v"(hi));
    return r;
}
__device__ __forceinline__ void gload16(const u16* g, u16* l) {
    __builtin_amdgcn_global_load_lds(
        (const __attribute__((address_space(1))) void*)g,
        (__attribute__((address_space(3))) void*)l, 16, 0, 0);
}

// ---- cast conv_w -> W2, t-major K, with As-swizzle baked into chunk order ----
// physical chunk jp of row co holds logical chunk jp ^ (co&7)
__global__ void k_cast_w(const float* __restrict__ cw, u16* __restrict__ W2) {
    int i = blockIdx.x * 256 + threadIdx.x;
    if (i >= C_ * KTOT) return;
    int co = i / KTOT, r = i % KTOT;
    int t = r >> 9, rem = r & 511;
    int kc = rem >> 6, cc = rem & 63;
    int jl = (cc >> 3) ^ (co & 7);
    int ci = kc * 64 + jl * 8 + (cc & 7);
    W2[i] = f2bf(cw[(co * C_ + ci) * 3 + t]);
}

// ---------------- anchors (float32 out) ----------------
__global__ void k_anchors(float* __restrict__ out) {
    int l = blockIdx.x * 256 + threadIdx.x;
    if (l >= LF) return;
    const float AL[7] = {1.f, 2.f, 3.f, 4.f, 5.f, 7.f, 9.f};
    float c = (float)l + 0.5f;
    float* an = out + ANC_OFF + (size_t)l * 14;
#pragma unroll
    for (int a = 0; a < 7; ++a) {
        an[a * 2 + 0] = c - 0.5f * AL[a];
        an[a * 2 + 1] = c + 0.5f * AL[a];
    }
}

// ---- conv GEMM (mt-loop inside) + fused head, direct f32 out ----
// grid: 1024 blocks = (l0 x 128, b x 8); 256 threads (4 waves, 2x2)
__global__ __launch_bounds__(256, 4) void k_conv_head(
    const float* __restrict__ feat, const u16* __restrict__ W2,
    const float* __restrict__ conv_b, const float* __restrict__ obj_w,
    const float* __restrict__ obj_bias, const float* __restrict__ reg_w,
    const float* __restrict__ reg_bias, float* __restrict__ out) {
    __shared__ __align__(16) char smem[40960];
    u16* As = (u16*)smem;                // [128][64] linear dest (swizzle in W2)
    u16* Bs = (u16*)(smem + 16384);      // [130][64] XOR-swizzled
    u16* Hs = (u16*)smem;                // [128][128] XOR-swizzled (epilogue)
    u16* Wp = (u16*)(smem + 32768);      // [32][128]  XOR-swizzled (epilogue)

    const int tid = threadIdx.x;
    const int lane = tid & 63, wave = tid >> 6;
    const int wm = wave >> 1, wn = wave & 1;
    const int g = lane >> 4, cL = lane & 15;
    const int l0 = (blockIdx.x & 127) * 128;
    const int b  = blockIdx.x >> 7;

    const int cg   = tid & 15;           // B-stage: ci0 = 4*cg
    const int lgrp = tid >> 4;           // B-stage: lbase = 8*lgrp
    const int arow = tid >> 3;           // A-stage row 0..31
    const int acol = (tid & 7) * 8;
    const int swA = (cL & 7) << 3;

    f32x4 hacc[2][2];
#pragma unroll
    for (int m = 0; m < 2; ++m)
#pragma unroll
        for (int n = 0; n < 2; ++n) hacc[m][n] = {0.f, 0.f, 0.f, 0.f};

    for (int mt = 0; mt < 4; ++mt) {
        const int co0 = mt * 128;
        f32x4 acc[4][4];
#pragma unroll
        for (int m = 0; m < 4; ++m)
#pragma unroll
            for (int n = 0; n < 4; ++n) acc[m][n] = {0.f, 0.f, 0.f, 0.f};

        for (int kc = 0; kc < 8; ++kc) {
            __syncthreads();             // prior readers of As/Bs (or Hs/Wp) done
            // ---- stage Bs rows 1..128 from feat (b64 swizzled writes) ----
            {
                const float* fp = feat +
                    ((size_t)(b * C_ + kc * 64 + cg * 4)) * LF + l0 + lgrp * 8;
#pragma unroll
                for (int h = 0; h < 2; ++h) {
                    float4 v0 = *(const float4*)(fp + 0 * LF + h * 4);
                    float4 v1 = *(const float4*)(fp + 1 * LF + h * 4);
                    float4 v2 = *(const float4*)(fp + 2 * LF + h * 4);
                    float4 v3 = *(const float4*)(fp + 3 * LF + h * 4);
#pragma unroll
                    for (int e = 0; e < 4; ++e) {
                        const int r = 1 + lgrp * 8 + h * 4 + e;
                        uint2 pk;
                        pk.x = pk2bf(((const float*)&v0)[e], ((const float*)&v1)[e]);
                        pk.y = pk2bf(((const float*)&v2)[e], ((const float*)&v3)[e]);
                        *(uint2*)&Bs[r * 64 + ((cg * 4) ^ ((r & 7) << 3))] = pk;
                    }
                }
            }
            // ---- halo rows r=0 (l0-1), r=129 (l0+128) ----
            if (tid < 128) {
                const int ci2 = tid >> 1;
                const int rr = (tid & 1) ? 129 : 0;
                const int l = l0 + rr - 1;
                float v = (l >= 0 && l < LF)
                              ? feat[((size_t)(b * C_ + kc * 64 + ci2)) * LF + l]
                              : 0.f;
                Bs[rr * 64 + (ci2 ^ ((rr & 7) << 3))] = f2bf(v);
            }
            // ---- taps ----
#pragma unroll
            for (int t = 0; t < 3; ++t) {
                if (t > 0) __syncthreads();
#pragma unroll
                for (int p = 0; p < 4; ++p) {
                    const int row = p * 32 + arow;
                    gload16(&W2[(size_t)(co0 + row) * KTOT + t * 512 + kc * 64 + acol],
                            &As[row * 64 + acol]);
                }
                __syncthreads();
                const int swB = ((cL + t) & 7) << 3;
#pragma unroll
                for (int kk = 0; kk < 2; ++kk) {
                    const int ko = kk * 32 + g * 8;
                    bh8 af[4], bfr[4];
#pragma unroll
                    for (int m = 0; m < 4; ++m)
                        af[m] = *(const bh8*)&As[(wm * 64 + m * 16 + cL) * 64 + (ko ^ swA)];
#pragma unroll
                    for (int n = 0; n < 4; ++n)
                        bfr[n] = *(const bh8*)&Bs[(wn * 64 + n * 16 + cL + t) * 64 + (ko ^ swB)];
#pragma unroll
                    for (int m = 0; m < 4; ++m)
#pragma unroll
                        for (int n = 0; n < 4; ++n)
                            acc[m][n] = __builtin_amdgcn_mfma_f32_16x16x32_bf16(
                                af[m], bfr[n], acc[m][n], 0, 0, 0);
                }
            }
        }
        __syncthreads();                 // K-loop LDS reads done

        // ---- epilogue: bias + relu -> Hs (swizzled b64 writes) ----
#pragma unroll
        for (int m = 0; m < 4; ++m) {
            const int co_b = wm * 64 + m * 16 + g * 4;
            const float b0_ = conv_b[co0 + co_b + 0];
            const float b1_ = conv_b[co0 + co_b + 1];
            const float b2_ = conv_b[co0 + co_b + 2];
            const float b3_ = conv_b[co0 + co_b + 3];
#pragma unroll
            for (int n = 0; n < 4; ++n) {
                const int l = wn * 64 + n * 16 + cL;
                f32x4 v = acc[m][n];
                uint2 pk;
                pk.x = pk2bf(fmaxf(v[0] + b0_, 0.f), fmaxf(v[1] + b1_, 0.f));
                pk.y = pk2bf(fmaxf(v[2] + b2_, 0.f), fmaxf(v[3] + b3_, 0.f));
                *(uint2*)&Hs[l * 128 + (co_b ^ ((cL & 7) << 3))] = pk;
            }
        }
        // ---- stage Wp[a][c] (a<7 obj, 7..20 reg, 21..31 zero), swizzled ----
#pragma unroll
        for (int it = 0; it < 4; ++it) {
            const int q = it * 256 + tid;
            const int a = q >> 5, c0 = (q & 31) * 4;
            float4 wv = {0.f, 0.f, 0.f, 0.f};
            if (a < 7)       wv = *(const float4*)&obj_w[a * C_ + co0 + c0];
            else if (a < 21) wv = *(const float4*)&reg_w[(a - 7) * C_ + co0 + c0];
            uint2 pk;
            pk.x = pk2bf(wv.x, wv.y);
            pk.y = pk2bf(wv.z, wv.w);
            *(uint2*)&Wp[a * 128 + (c0 ^ ((a & 7) << 3))] = pk;
        }
        __syncthreads();

        // ---- head MFMA: hacc[a][l] += sum_c Wp[a][c] * Hs[l][c] ----
        const int ln0 = wave * 32;
#pragma unroll
        for (int ks2 = 0; ks2 < 4; ++ks2) {
            const int ko = ks2 * 32 + g * 8;
            bh8 wa[2], hb[2];
            wa[0] = *(const bh8*)&Wp[cL * 128 + (ko ^ swA)];
            wa[1] = *(const bh8*)&Wp[(16 + cL) * 128 + (ko ^ swA)];
            hb[0] = *(const bh8*)&Hs[(ln0 + cL) * 128 + (ko ^ swA)];
            hb[1] = *(const bh8*)&Hs[(ln0 + 16 + cL) * 128 + (ko ^ swA)];
#pragma unroll
            for (int m = 0; m < 2; ++m)
#pragma unroll
                for (int n = 0; n < 2; ++n)
                    hacc[m][n] = __builtin_amdgcn_mfma_f32_16x16x32_bf16(
                        wa[m], hb[n], hacc[m][n], 0, 0, 0);
        }
    }

    // ---- final write: obj/reg with biases ----
    const int ln0 = wave * 32;
#pragma unroll
    for (int m = 0; m < 2; ++m) {
        const int a0 = m * 16 + g * 4;
#pragma unroll
        for (int n = 0; n < 2; ++n) {
            const int l = l0 + ln0 + n * 16 + cL;
#pragma unroll
            for (int r = 0; r < 4; ++r) {
                const int a = a0 + r;
                float v = hacc[m][n][r];
                if (a < 7)
                    out[OBJ_OFF + (size_t)b * (LF * 7) + (size_t)l * 7 + a] = v + obj_bias[a];
                else if (a < 21)
                    out[REG_OFF + (size_t)b * (LF * 14) + (size_t)l * 14 + (a - 7)] =
                        v + reg_bias[a - 7];
            }
        }
    }
}

extern "C" void kernel_launch(void* const* d_in, const int* in_sizes, int n_in,
                              void* d_out, int out_size, void* d_ws, size_t ws_size,
                              hipStream_t stream) {
    const float* feat   = (const float*)d_in[0];
    const float* conv_w = (const float*)d_in[1];
    const float* conv_b = (const float*)d_in[2];
    const float* obj_w  = (const float*)d_in[3];
    const float* obj_b  = (const float*)d_in[4];
    const float* reg_w  = (const float*)d_in[5];
    const float* reg_b  = (const float*)d_in[6];
    u16* W2 = (u16*)d_ws;
    float* out = (float*)d_out;

    k_cast_w<<<3072, 256, 0, stream>>>(conv_w, W2);
    k_anchors<<<64, 256, 0, stream>>>(out);
    k_conv_head<<<1024, 256, 0, stream>>>(feat, W2, conv_b, obj_w, obj_b,
                                          reg_w, reg_b, out);
}

// Round 8
// 266.084 us; speedup vs baseline: 1.6228x; 1.6228x over previous
//
#include <hip/hip_runtime.h>
#include <hip/hip_bf16.h>
#include <stdint.h>

typedef __attribute__((ext_vector_type(8))) short bh8;
typedef __attribute__((ext_vector_type(4))) float f32x4;
typedef unsigned short u16;
typedef unsigned int u32;

#define B_    8
#define C_    512
#define LF    16384
#define KTOT  1536

// ws layout (bytes)
#define P4_BYTES ((size_t)4 * B_ * 21 * LF * 4)      // 44,040,192
#define W2_OFF   P4_BYTES

// output chunk offsets (float32 elements)
#define OBJ_OFF  0
#define REG_OFF  917504      // 8 * 16384*7
#define ANC_OFF  2752512     // REG_OFF + 8*16384*14

__device__ __forceinline__ u16 f2bf(float f) {
    u32 u = __float_as_uint(f);
    return (u16)((u + 0x7FFFu + ((u >> 16) & 1u)) >> 16);
}
__device__ __forceinline__ u32 pk2bf(float lo, float hi) {
    u32 r;
    asm("v_cvt_pk_bf16_f32 %0, %1, %2" : "=v"(r) : "v"(lo), "v"(hi));
    return r;
}
__device__ __forceinline__ void gload16(const u16* g, u16* l) {
    __builtin_amdgcn_global_load_lds(
        (const __attribute__((address_space(1))) void*)g,
        (__attribute__((address_space(3))) void*)l, 16, 0, 0);
}

// ---- cast conv_w -> W2, t-major K, As-swizzle baked into chunk order ----
// physical chunk jp of row co holds logical chunk jp ^ (co&7)
__global__ void k_cast_w(const float* __restrict__ cw, u16* __restrict__ W2) {
    int i = blockIdx.x * 256 + threadIdx.x;
    if (i >= C_ * KTOT) return;
    int co = i / KTOT, r = i % KTOT;
    int t = r >> 9, rem = r & 511;
    int kc = rem >> 6, cc = rem & 63;
    int jl = (cc >> 3) ^ (co & 7);
    int ci = kc * 64 + jl * 8 + (cc & 7);
    W2[i] = f2bf(cw[(co * C_ + ci) * 3 + t]);
}

// ---------------- anchors (float32 out) ----------------
__global__ void k_anchors(float* __restrict__ out) {
    int l = blockIdx.x * 256 + threadIdx.x;
    if (l >= LF) return;
    const float AL[7] = {1.f, 2.f, 3.f, 4.f, 5.f, 7.f, 9.f};
    float c = (float)l + 0.5f;
    float* an = out + ANC_OFF + (size_t)l * 14;
#pragma unroll
    for (int a = 0; a < 7; ++a) {
        an[a * 2 + 0] = c - 0.5f * AL[a];
        an[a * 2 + 1] = c + 0.5f * AL[a];
    }
}

// ---- conv GEMM (mt in grid, XCD-swizzled mt-quads) + fused head -> P4 ----
// grid: 4096 blocks; 256 threads (4 waves, 2x2)
__global__ __launch_bounds__(256, 4) void k_conv_head(
    const float* __restrict__ feat, const u16* __restrict__ W2,
    const float* __restrict__ conv_b, const float* __restrict__ obj_w,
    const float* __restrict__ reg_w, float* __restrict__ P4) {
    __shared__ __align__(16) char smem[40960];
    u16* As = (u16*)smem;                // [128][64] linear dest (swizzle in W2)
    u16* Bs = (u16*)(smem + 16384);      // [130][64] XOR-swizzled
    u16* Hs = (u16*)smem;                // [128][128] XOR-swizzled (epilogue)
    u16* Wp = (u16*)(smem + 32768);      // [32][128]  XOR-swizzled (epilogue)

    const int tid = threadIdx.x;
    const int lane = tid & 63, wave = tid >> 6;
    const int wm = wave >> 1, wn = wave & 1;
    const int g = lane >> 4, cL = lane & 15;

    // XCD swizzle: consecutive wg on one XCD iterate mt fastest (share feat slice)
    const int wg = (blockIdx.x & 7) * 512 + (blockIdx.x >> 3);
    const int mt = wg & 3;
    const int l0 = ((wg >> 2) & 127) * 128;
    const int b  = wg >> 9;
    const int co0 = mt * 128;

    const int cg   = tid & 15;           // B-stage: ci0 = 4*cg
    const int lgrp = tid >> 4;           // B-stage: lbase = 8*lgrp
    const int arow = tid >> 3;           // A-stage row 0..31
    const int acol = (tid & 7) * 8;
    const int swA = (cL & 7) << 3;

    f32x4 acc[4][4];
#pragma unroll
    for (int m = 0; m < 4; ++m)
#pragma unroll
        for (int n = 0; n < 4; ++n) acc[m][n] = {0.f, 0.f, 0.f, 0.f};

    for (int kc = 0; kc < 8; ++kc) {
        __syncthreads();                 // prior readers of As/Bs done
        // ---- stage Bs rows 1..128 from feat (pk2bf + b64 swizzled writes) ----
        {
            const float* fp = feat +
                ((size_t)(b * C_ + kc * 64 + cg * 4)) * LF + l0 + lgrp * 8;
#pragma unroll
            for (int h = 0; h < 2; ++h) {
                float4 v0 = *(const float4*)(fp + 0 * LF + h * 4);
                float4 v1 = *(const float4*)(fp + 1 * LF + h * 4);
                float4 v2 = *(const float4*)(fp + 2 * LF + h * 4);
                float4 v3 = *(const float4*)(fp + 3 * LF + h * 4);
#pragma unroll
                for (int e = 0; e < 4; ++e) {
                    const int r = 1 + lgrp * 8 + h * 4 + e;
                    uint2 pk;
                    pk.x = pk2bf(((const float*)&v0)[e], ((const float*)&v1)[e]);
                    pk.y = pk2bf(((const float*)&v2)[e], ((const float*)&v3)[e]);
                    *(uint2*)&Bs[r * 64 + ((cg * 4) ^ ((r & 7) << 3))] = pk;
                }
            }
        }
        // ---- halo rows r=0 (l0-1), r=129 (l0+128) ----
        if (tid < 128) {
            const int ci2 = tid >> 1;
            const int rr = (tid & 1) ? 129 : 0;
            const int l = l0 + rr - 1;
            float v = (l >= 0 && l < LF)
                          ? feat[((size_t)(b * C_ + kc * 64 + ci2)) * LF + l]
                          : 0.f;
            Bs[rr * 64 + (ci2 ^ ((rr & 7) << 3))] = f2bf(v);
        }
        // ---- taps ----
#pragma unroll
        for (int t = 0; t < 3; ++t) {
            if (t > 0) __syncthreads();
#pragma unroll
            for (int p = 0; p < 4; ++p) {
                const int row = p * 32 + arow;
                gload16(&W2[(size_t)(co0 + row) * KTOT + t * 512 + kc * 64 + acol],
                        &As[row * 64 + acol]);
            }
            __syncthreads();
            const int swB = ((cL + t) & 7) << 3;
#pragma unroll
            for (int kk = 0; kk < 2; ++kk) {
                const int ko = kk * 32 + g * 8;
                bh8 af[4], bfr[4];
#pragma unroll
                for (int m = 0; m < 4; ++m)
                    af[m] = *(const bh8*)&As[(wm * 64 + m * 16 + cL) * 64 + (ko ^ swA)];
#pragma unroll
                for (int n = 0; n < 4; ++n)
                    bfr[n] = *(const bh8*)&Bs[(wn * 64 + n * 16 + cL + t) * 64 + (ko ^ swB)];
#pragma unroll
                for (int m = 0; m < 4; ++m)
#pragma unroll
                    for (int n = 0; n < 4; ++n)
                        acc[m][n] = __builtin_amdgcn_mfma_f32_16x16x32_bf16(
                            af[m], bfr[n], acc[m][n], 0, 0, 0);
            }
        }
    }
    __syncthreads();                     // K-loop LDS reads done

    // ---- epilogue: bias + relu -> Hs (swizzled b64 writes) ----
#pragma unroll
    for (int m = 0; m < 4; ++m) {
        const int co_b = wm * 64 + m * 16 + g * 4;
        const float b0_ = conv_b[co0 + co_b + 0];
        const float b1_ = conv_b[co0 + co_b + 1];
        const float b2_ = conv_b[co0 + co_b + 2];
        const float b3_ = conv_b[co0 + co_b + 3];
#pragma unroll
        for (int n = 0; n < 4; ++n) {
            const int l = wn * 64 + n * 16 + cL;
            f32x4 v = acc[m][n];
            uint2 pk;
            pk.x = pk2bf(fmaxf(v[0] + b0_, 0.f), fmaxf(v[1] + b1_, 0.f));
            pk.y = pk2bf(fmaxf(v[2] + b2_, 0.f), fmaxf(v[3] + b3_, 0.f));
            *(uint2*)&Hs[l * 128 + (co_b ^ ((cL & 7) << 3))] = pk;
        }
    }
    // ---- stage Wp[a][c] (a<7 obj, 7..20 reg, 21..31 zero), swizzled ----
#pragma unroll
    for (int it = 0; it < 4; ++it) {
        const int q = it * 256 + tid;
        const int a = q >> 5, c0 = (q & 31) * 4;
        float4 wv = {0.f, 0.f, 0.f, 0.f};
        if (a < 7)       wv = *(const float4*)&obj_w[a * C_ + co0 + c0];
        else if (a < 21) wv = *(const float4*)&reg_w[(a - 7) * C_ + co0 + c0];
        uint2 pk;
        pk.x = pk2bf(wv.x, wv.y);
        pk.y = pk2bf(wv.z, wv.w);
        *(uint2*)&Wp[a * 128 + (c0 ^ ((a & 7) << 3))] = pk;
    }
    __syncthreads();

    // ---- head MFMA: D[a][l] = sum_c Wp[a][c] * Hs[l][c] ----
    f32x4 hacc[2][2];
#pragma unroll
    for (int m = 0; m < 2; ++m)
#pragma unroll
        for (int n = 0; n < 2; ++n) hacc[m][n] = {0.f, 0.f, 0.f, 0.f};
    const int ln0 = wave * 32;
#pragma unroll
    for (int ks2 = 0; ks2 < 4; ++ks2) {
        const int ko = ks2 * 32 + g * 8;
        bh8 wa[2], hb[2];
        wa[0] = *(const bh8*)&Wp[cL * 128 + (ko ^ swA)];
        wa[1] = *(const bh8*)&Wp[(16 + cL) * 128 + (ko ^ swA)];
        hb[0] = *(const bh8*)&Hs[(ln0 + cL) * 128 + (ko ^ swA)];
        hb[1] = *(const bh8*)&Hs[(ln0 + 16 + cL) * 128 + (ko ^ swA)];
#pragma unroll
        for (int m = 0; m < 2; ++m)
#pragma unroll
            for (int n = 0; n < 2; ++n)
                hacc[m][n] = __builtin_amdgcn_mfma_f32_16x16x32_bf16(
                    wa[m], hb[n], hacc[m][n], 0, 0, 0);
    }
    // ---- store partials: P4[mt][b][a][l] ----
    float* P4base = P4 + ((size_t)(mt * B_ + b) * 21) * LF + l0;
#pragma unroll
    for (int m = 0; m < 2; ++m) {
        const int a0 = m * 16 + g * 4;
#pragma unroll
        for (int n = 0; n < 2; ++n) {
            const int l = ln0 + n * 16 + cL;
#pragma unroll
            for (int r = 0; r < 4; ++r) {
                const int a = a0 + r;
                if (a < 21) P4base[(size_t)a * LF + l] = hacc[m][n][r];
            }
        }
    }
}

// ---------------- reduce partials, add biases, write f32 obj/reg ----------------
__global__ void k_finalize(const float* __restrict__ P4, const float* __restrict__ obj_b,
                           const float* __restrict__ reg_b, float* __restrict__ out) {
    int gid = blockIdx.x * 256 + threadIdx.x;
    if (gid >= B_ * LF) return;
    int b = gid >> 14, l = gid & (LF - 1);
    float s[21];
#pragma unroll
    for (int a = 0; a < 21; ++a) {
        float v = 0.f;
#pragma unroll
        for (int m = 0; m < 4; ++m) v += P4[((size_t)(m * B_ + b) * 21 + a) * LF + l];
        s[a] = v;
    }
    float* op = out + OBJ_OFF + (size_t)b * (LF * 7) + (size_t)l * 7;
#pragma unroll
    for (int a = 0; a < 7; ++a) op[a] = s[a] + obj_b[a];
    float* rp = out + REG_OFF + (size_t)b * (LF * 14) + (size_t)l * 14;
#pragma unroll
    for (int o = 0; o < 14; ++o) rp[o] = s[7 + o] + reg_b[o];
}

extern "C" void kernel_launch(void* const* d_in, const int* in_sizes, int n_in,
                              void* d_out, int out_size, void* d_ws, size_t ws_size,
                              hipStream_t stream) {
    const float* feat   = (const float*)d_in[0];
    const float* conv_w = (const float*)d_in[1];
    const float* conv_b = (const float*)d_in[2];
    const float* obj_w  = (const float*)d_in[3];
    const float* obj_b  = (const float*)d_in[4];
    const float* reg_w  = (const float*)d_in[5];
    const float* reg_b  = (const float*)d_in[6];
    char* ws = (char*)d_ws;
    float* P4 = (float*)ws;
    u16* W2   = (u16*)(ws + W2_OFF);
    float* out = (float*)d_out;

    k_cast_w<<<3072, 256, 0, stream>>>(conv_w, W2);
    k_anchors<<<64, 256, 0, stream>>>(out);
    k_conv_head<<<4096, 256, 0, stream>>>(feat, W2, conv_b, obj_w, reg_w, P4);
    k_finalize<<<(B_ * LF + 255) / 256, 256, 0, stream>>>(P4, obj_b, reg_b, out);
}